// Round 6
// baseline (150.278 us; speedup 1.0000x reference)
//
#include <hip/hip_runtime.h>
#include <hip/hip_cooperative_groups.h>
#include <math.h>

namespace cg = cooperative_groups;

// Shapes from reference: B=4, N=256, D=128, M=128, C=128
#define BB 4
#define NN 256
#define DD 128
#define MM 128
#define CC 128
#define ROWS (BB * NN)   // 1024

static __device__ __forceinline__ float fast_exp2(float x) {
#if __has_builtin(__builtin_amdgcn_exp2f)
    return __builtin_amdgcn_exp2f(x);
#else
    return __exp2f(x);
#endif
}

static __device__ __forceinline__ float fast_rcp(float x) {
#if __has_builtin(__builtin_amdgcn_rcpf)
    return __builtin_amdgcn_rcpf(x);
#else
    return 1.0f / x;
#endif
}

// silu(x) = x / (1 + exp(-x)); exp(-x) = 2^(-x*log2(e))
static __device__ __forceinline__ float silu_f(float x) {
    float e = fast_exp2(-1.44269504088896340736f * x);
    return x * fast_rcp(1.0f + e);
}

// One 128x128 matvec over 4 LDS-resident rows.
// k = t&127, half = t>>7 covers dd in [half*32, half*32+32) per 64-row chunk.
// Cross-half combine through sP. IMPORTANT: callers must put any bias into
// acc for half==0 ONLY (half==1's acc is folded into half==0's at the end —
// a bias in both halves would be double-counted).
static __device__ __forceinline__ void mat128(const float* __restrict__ W,
                                              const float* __restrict__ src,  // LDS [4*MM]
                                              float* __restrict__ sW,         // LDS staging 32 KB
                                              float* __restrict__ sP,         // LDS [4*MM]
                                              float acc[4], int t, int k, int half) {
    for (int c = 0; c < 2; ++c) {
        __syncthreads();                       // protect sW readers / src writers
        const float4* g = (const float4*)(W + (size_t)c * 64 * MM);
        float4* l = (float4*)sW;
        #pragma unroll
        for (int i = 0; i < 8; ++i) l[t + 256 * i] = g[t + 256 * i];
        __syncthreads();

        const int dd0 = half * 32;
        #pragma unroll 8
        for (int dd = dd0; dd < dd0 + 32; ++dd) {
            const int d = c * 64 + dd;
            const float wv = sW[dd * MM + k];          // stride-1: conflict-free
            #pragma unroll
            for (int r = 0; r < 4; ++r) acc[r] = fmaf(src[r * MM + d], wv, acc[r]);
        }
    }
    if (half == 1) {
        #pragma unroll
        for (int r = 0; r < 4; ++r) sP[r * MM + k] = acc[r];
    }
    __syncthreads();
    if (half == 0) {
        #pragma unroll
        for (int r = 0; r < 4; ++r) acc[r] += sP[r * MM + k];
    }
}

__global__ __launch_bounds__(256) void fused(const float* __restrict__ h,
                                             const float* __restrict__ adj,
                                             const float* __restrict__ W1a,
                                             const float* __restrict__ W1b,
                                             const float* __restrict__ b1,
                                             const float* __restrict__ W2,
                                             const float* __restrict__ b2,
                                             const float* __restrict__ Wc1,
                                             const float* __restrict__ bc1,
                                             const float* __restrict__ Wc2,
                                             const float* __restrict__ bc2,
                                             float* __restrict__ out,
                                             float* __restrict__ pjws) {
    __shared__ float sStage[64 * MM];   // 32 KB: weight / pj chunk staging
    __shared__ float sH[4 * DD];        // 2 KB
    __shared__ float sPib[4 * MM];      // 2 KB: pibias for own 4 rows
    __shared__ float sAdj[4][NN];       // 4 KB
    __shared__ float sRed[4 * 256];     // 4 KB: reductions / phase-3 partials
    __shared__ float sS[4 * MM];        // 2 KB: S rows (phase 2 -> 3)
    __shared__ float sB[4 * MM];        // 2 KB: magg (phase 3 ping)
    __shared__ float sWred[4][4];

    const int t = threadIdx.x;
    const int blk = blockIdx.x;         // 256 blocks; block owns rows 4*blk..4*blk+3
    const int row0 = blk * 4;
    const int b = blk >> 6;             // batch (64 blocks per batch)
    const int i0 = (blk & 63) * 4;      // first i within batch

    const int m = t & 127;
    const int half = t >> 7;

    // Hoisted loads (cold L2; latency hidden behind phase 1).
    const float b1m  = b1[m];
    const float b2k  = b2[m];
    const float bc1k = bc1[m];
    const float bc2k = bc2[m];

    // ================= Phase 1: pibias/pj = h@W1a + b1 / h@W1b =================
    {
        const float* hbase = h + (size_t)row0 * DD;
        sH[t] = hbase[t];
        sH[t + 256] = hbase[t + 256];

        float accA0 = 0.f, accA1 = 0.f, accB0 = 0.f, accB1 = 0.f;
        for (int c = 0; c < 4; ++c) {
            __syncthreads();
            const float4* ga = (const float4*)(W1a + (size_t)c * 32 * MM);
            const float4* gb = (const float4*)(W1b + (size_t)c * 32 * MM);
            float4* la = (float4*)sStage;               // [0, 16 KB)
            float4* lb = (float4*)(sStage + 32 * MM);   // [16, 32 KB)
            #pragma unroll
            for (int i = 0; i < 4; ++i) {
                la[t + 256 * i] = ga[t + 256 * i];
                lb[t + 256 * i] = gb[t + 256 * i];
            }
            __syncthreads();
            #pragma unroll 8
            for (int dd = 0; dd < 32; ++dd) {
                const int d = c * 32 + dd;
                const float wa = sStage[dd * MM + m];
                const float wb = sStage[32 * MM + dd * MM + m];
                const float h0 = sH[(half * 2 + 0) * DD + d];   // uniform broadcast
                const float h1 = sH[(half * 2 + 1) * DD + d];
                accA0 = fmaf(h0, wa, accA0);
                accA1 = fmaf(h1, wa, accA1);
                accB0 = fmaf(h0, wb, accB0);
                accB1 = fmaf(h1, wb, accB1);
            }
        }
        sPib[(half * 2 + 0) * MM + m] = accA0 + b1m;
        sPib[(half * 2 + 1) * MM + m] = accA1 + b1m;
        float* pjrow = pjws + (size_t)(row0 + half * 2) * MM;
        pjrow[m]      = accB0;
        pjrow[MM + m] = accB1;
    }

    cg::this_grid().sync();   // pj fully visible device-wide

    // ================= Phase 2: S, beta (own 4 rows) =================
    float inv[4], bet[4];
    {
        // Stage 4 adj rows (1024 floats).
        const float* arow = adj + (size_t)row0 * NN;
        float* sAdjF = (float*)sAdj;
        #pragma unroll
        for (int i = 0; i < 4; ++i) sAdjF[t + 256 * i] = arow[t + 256 * i];
        __syncthreads();

        // Row sums via shuffle (4 rows interleaved for ILP).
        float v0 = sAdj[0][t], v1 = sAdj[1][t], v2 = sAdj[2][t], v3 = sAdj[3][t];
        #pragma unroll
        for (int off = 32; off > 0; off >>= 1) {
            v0 += __shfl_xor(v0, off, 64);
            v1 += __shfl_xor(v1, off, 64);
            v2 += __shfl_xor(v2, off, 64);
            v3 += __shfl_xor(v3, off, 64);
        }
        if ((t & 63) == 0) {
            const int w = t >> 6;
            sWred[0][w] = v0; sWred[1][w] = v1; sWred[2][w] = v2; sWred[3][w] = v3;
        }
        __syncthreads();
        float A[4], aii[4];
        #pragma unroll
        for (int r = 0; r < 4; ++r) {
            A[r] = sWred[r][0] + sWred[r][1] + sWred[r][2] + sWred[r][3];
            aii[r] = sAdj[r][i0 + r];
        }
        __syncthreads();                 // all aii reads done before zeroing
        if (t < 4) sAdj[t][i0 + t] = 0.0f;
        #pragma unroll
        for (int r = 0; r < 4; ++r) {
            inv[r] = 1.0f / fmaxf(A[r], 1.0f);
            bet[r] = (A[r] - aii[r]) * inv[r];
        }

        const float pim0 = sPib[0 * MM + m];
        const float pim1 = sPib[1 * MM + m];
        const float pim2 = sPib[2 * MM + m];
        const float pim3 = sPib[3 * MM + m];
        const float* __restrict__ pjB = pjws + (size_t)b * NN * MM;

        float acc0 = 0.f, acc1 = 0.f, acc2 = 0.f, acc3 = 0.f;
        for (int c = 0; c < 4; ++c) {
            __syncthreads();             // also covers the diagonal zeroing (c=0)
            const float4* g = (const float4*)(pjB + (size_t)c * 64 * MM);
            float4* l = (float4*)sStage;
            #pragma unroll
            for (int i = 0; i < 8; ++i) l[t + 256 * i] = g[t + 256 * i];
            __syncthreads();

            #pragma unroll 4
            for (int jj = half; jj < 64; jj += 2) {
                const int j = c * 64 + jj;
                const float pjv = sStage[jj * MM + m];    // stride-1: conflict-free
                const float w0 = sAdj[0][j];              // wave-uniform broadcast
                const float w1 = sAdj[1][j];
                const float w2 = sAdj[2][j];
                const float w3 = sAdj[3][j];
                acc0 = fmaf(w0, silu_f(pim0 + pjv), acc0);
                acc1 = fmaf(w1, silu_f(pim1 + pjv), acc1);
                acc2 = fmaf(w2, silu_f(pim2 + pjv), acc2);
                acc3 = fmaf(w3, silu_f(pim3 + pjv), acc3);
            }
        }

        sRed[0 * 256 + t] = acc0;
        sRed[1 * 256 + t] = acc1;
        sRed[2 * 256 + t] = acc2;
        sRed[3 * 256 + t] = acc3;
        __syncthreads();
        if (t < 128) {
            #pragma unroll
            for (int r = 0; r < 4; ++r)
                sS[r * MM + t] = (sRed[r * 256 + t] + sRed[r * 256 + t + 128]) * inv[r];
        }
        // next mat128's leading __syncthreads covers sS visibility
    }

    // ================= Phase 3: out = silu((S@W2+beta*b2)@Wc1+bc1)@Wc2 + bc2 ====
    {
        float acc[4];

        // Stage 1: magg = S@W2 + beta*b2  (sS -> sB). Bias in half 0 ONLY.
        #pragma unroll
        for (int r = 0; r < 4; ++r) acc[r] = (half == 0) ? bet[r] * b2k : 0.0f;
        mat128(W2, sS, sStage, sRed, acc, t, m, half);
        if (half == 0) {
            #pragma unroll
            for (int r = 0; r < 4; ++r) sB[r * MM + m] = acc[r];
        }

        // Stage 2: t1 = silu(magg@Wc1 + bc1)  (sB -> sS). Bias in half 0 ONLY.
        #pragma unroll
        for (int r = 0; r < 4; ++r) acc[r] = (half == 0) ? bc1k : 0.0f;
        mat128(Wc1, sB, sStage, sRed, acc, t, m, half);
        if (half == 0) {
            #pragma unroll
            for (int r = 0; r < 4; ++r) sS[r * MM + m] = silu_f(acc[r]);
        }

        // Stage 3: out = t1@Wc2 + bc2  (sS -> global). Bias in half 0 ONLY.
        #pragma unroll
        for (int r = 0; r < 4; ++r) acc[r] = (half == 0) ? bc2k : 0.0f;
        mat128(Wc2, sS, sStage, sRed, acc, t, m, half);
        if (half == 0) {
            #pragma unroll
            for (int r = 0; r < 4; ++r)
                out[(size_t)(row0 + r) * CC + m] = acc[r];
        }
    }
}

extern "C" void kernel_launch(void* const* d_in, const int* in_sizes, int n_in,
                              void* d_out, int out_size, void* d_ws, size_t ws_size,
                              hipStream_t stream) {
    const float* h   = (const float*)d_in[0];
    const float* adj = (const float*)d_in[1];
    const float* W1a = (const float*)d_in[2];
    const float* W1b = (const float*)d_in[3];
    const float* b1  = (const float*)d_in[4];
    const float* W2  = (const float*)d_in[5];
    const float* b2  = (const float*)d_in[6];
    const float* Wc1 = (const float*)d_in[7];
    const float* bc1 = (const float*)d_in[8];
    const float* Wc2 = (const float*)d_in[9];
    const float* bc2 = (const float*)d_in[10];
    float* out = (float*)d_out;
    float* pjws = (float*)d_ws;    // 1024*128 floats = 512 KB

    void* args[] = {(void*)&h, (void*)&adj, (void*)&W1a, (void*)&W1b, (void*)&b1,
                    (void*)&W2, (void*)&b2, (void*)&Wc1, (void*)&bc1,
                    (void*)&Wc2, (void*)&bc2, (void*)&out, (void*)&pjws};
    hipLaunchCooperativeKernel(reinterpret_cast<void*>(fused),
                               dim3(256), dim3(256), args, 0, stream);
}

// Round 7
// 101.961 us; speedup vs baseline: 1.4739x; 1.4739x over previous
//
#include <hip/hip_runtime.h>
#include <math.h>

// Shapes from reference: B=4, N=256, D=128, M=128, C=128
#define BB 4
#define NN 256
#define DD 128
#define MM 128
#define CC 128
#define ROWS (BB * NN)   // 1024

static __device__ __forceinline__ float fast_exp2(float x) {
#if __has_builtin(__builtin_amdgcn_exp2f)
    return __builtin_amdgcn_exp2f(x);
#else
    return __exp2f(x);
#endif
}

static __device__ __forceinline__ float fast_rcp(float x) {
#if __has_builtin(__builtin_amdgcn_rcpf)
    return __builtin_amdgcn_rcpf(x);
#else
    return 1.0f / x;
#endif
}

// silu(x) = x / (1 + exp(-x)); exp(-x) = 2^(-x*log2(e))
static __device__ __forceinline__ float silu_f(float x) {
    float e = fast_exp2(-1.44269504088896340736f * x);
    return x * fast_rcp(1.0f + e);
}

// ---------------------------------------------------------------------------
// Kernel A: pibias = h@W1a + b1 ; pj = h@W1b
// 512 blocks (2 rows each) x 256 threads: m = t&127, r = t>>7 (one row per
// thread-half; full 128-d dot per thread -> no cross-half combine).
// Weights burst-staged in 4 chunks of (16+16) KB; 2 blocks/CU overlap
// staging latency with the other block's compute.
// ---------------------------------------------------------------------------
__global__ __launch_bounds__(256) void k_proj(const float* __restrict__ h,
                                              const float* __restrict__ W1a,
                                              const float* __restrict__ W1b,
                                              const float* __restrict__ b1,
                                              float* __restrict__ pibias,
                                              float* __restrict__ pj) {
    __shared__ float sWa[32 * MM];   // 16 KB
    __shared__ float sWb[32 * MM];   // 16 KB
    __shared__ float sH[2 * DD];     // 1 KB

    const int t = threadIdx.x;
    const int m = t & 127;
    const int r = t >> 7;
    const int row0 = blockIdx.x * 2;

    const float bias = b1[m];        // early load

    // Stage 2 h rows (256 floats).
    sH[t] = h[(size_t)row0 * DD + t];

    float accA = 0.0f, accB = 0.0f;
    for (int c = 0; c < 4; ++c) {
        __syncthreads();             // protects prev chunk readers (and sH on c=0)
        const float4* ga = (const float4*)(W1a + (size_t)c * 32 * MM);
        const float4* gb = (const float4*)(W1b + (size_t)c * 32 * MM);
        float4* la = (float4*)sWa;
        float4* lb = (float4*)sWb;
        #pragma unroll
        for (int i = 0; i < 4; ++i) {
            la[t + 256 * i] = ga[t + 256 * i];
            lb[t + 256 * i] = gb[t + 256 * i];
        }
        __syncthreads();

        #pragma unroll 8
        for (int dd = 0; dd < 32; ++dd) {
            const int d = c * 32 + dd;
            const float hv = sH[r * DD + d];        // wave-uniform broadcast
            accA = fmaf(hv, sWa[dd * MM + m], accA);
            accB = fmaf(hv, sWb[dd * MM + m], accB);
        }
    }

    const int row = row0 + r;
    pibias[(size_t)row * MM + m] = accA + bias;
    pj[(size_t)row * MM + m]     = accB;
}

// ---------------------------------------------------------------------------
// Kernel B: fused msg + output head, 2 rows per block, 512 blocks x 256 thr.
// Phase A (msg): S[r][m] = inv*sum_{j!=i} adj*silu(pibias+pj) ; beta = ...
//   (m = t&127, jh = t>>7; pj staged in 4 x 32 KB chunks, shared by 2 rows)
// Phase B (head): magg = S@W2 + beta*b2 ; t1 = silu(magg@Wc1+bc1) ;
//   out = t1@Wc2 + bc2.  (k = t&127, r = t>>7: full 128-d dot per thread,
//   bias added exactly once per thread -> no double-bias hazard)
// S/beta live in LDS only; never touch global.
// ---------------------------------------------------------------------------
__global__ __launch_bounds__(256) void k_msgout(const float* __restrict__ adj,
                                                const float* __restrict__ pibias,
                                                const float* __restrict__ pj,
                                                const float* __restrict__ W2,
                                                const float* __restrict__ b2,
                                                const float* __restrict__ Wc1,
                                                const float* __restrict__ bc1,
                                                const float* __restrict__ Wc2,
                                                const float* __restrict__ bc2,
                                                float* __restrict__ out) {
    __shared__ float sStage[64 * MM];  // 32 KB: pj / weight chunk staging
    __shared__ float sAdj[2][NN];      // 2 KB
    __shared__ float sRed[2][256];     // 2 KB
    __shared__ float sS[2 * MM];       // 1 KB: S rows (also t1 later)
    __shared__ float sB[2 * MM];       // 1 KB: magg
    __shared__ float sWred[2][4];

    const int t = threadIdx.x;
    const int blk = blockIdx.x;        // 512 blocks
    const int b = blk >> 7;            // batch (128 blocks per batch)
    const int i0 = (blk & 127) * 2;
    const int row0 = b * NN + i0;

    const int m = t & 127;
    const int half = t >> 7;

    // Early independent loads.
    const float b2k  = b2[m];
    const float bc1k = bc1[m];
    const float bc2k = bc2[m];
    const float pim0 = pibias[(size_t)row0 * MM + m];
    const float pim1 = pibias[(size_t)(row0 + 1) * MM + m];

    // Stage both adj rows (512 floats).
    const float* arow = adj + (size_t)row0 * NN;
    const float a0v = arow[t];
    const float a1v = arow[t + 256];
    sAdj[0][t] = a0v;
    sAdj[1][t] = a1v;
    __syncthreads();

    // Row sums via wave shuffle + tiny LDS combine.
    float v0 = a0v, v1 = a1v;
    #pragma unroll
    for (int off = 32; off > 0; off >>= 1) {
        v0 += __shfl_xor(v0, off, 64);
        v1 += __shfl_xor(v1, off, 64);
    }
    if ((t & 63) == 0) { sWred[0][t >> 6] = v0; sWred[1][t >> 6] = v1; }
    __syncthreads();
    const float A0 = sWred[0][0] + sWred[0][1] + sWred[0][2] + sWred[0][3];
    const float A1 = sWred[1][0] + sWred[1][1] + sWred[1][2] + sWred[1][3];
    const float aii0 = sAdj[0][i0];
    const float aii1 = sAdj[1][i0 + 1];
    __syncthreads();                   // all reads done before zeroing
    if (t == 0) { sAdj[0][i0] = 0.0f; sAdj[1][i0 + 1] = 0.0f; }

    const float inv0 = 1.0f / fmaxf(A0, 1.0f);
    const float inv1 = 1.0f / fmaxf(A1, 1.0f);
    const float bet0 = (A0 - aii0) * inv0;
    const float bet1 = (A1 - aii1) * inv1;

    // ---- Phase A: weighted-silu reduction over j (pj staged in 4 chunks)
    const float* __restrict__ pjB = pj + (size_t)b * NN * MM;
    float acc0 = 0.0f, acc1 = 0.0f;
    for (int c = 0; c < 4; ++c) {
        __syncthreads();               // covers diagonal zeroing on c=0
        const float4* g = (const float4*)(pjB + (size_t)c * 64 * MM);
        float4* l = (float4*)sStage;
        #pragma unroll
        for (int i = 0; i < 8; ++i) l[t + 256 * i] = g[t + 256 * i];
        __syncthreads();

        #pragma unroll 8
        for (int jj = half; jj < 64; jj += 2) {
            const int j = c * 64 + jj;
            const float pjv = sStage[jj * MM + m];    // stride-1: conflict-free
            const float w0 = sAdj[0][j];              // wave-uniform broadcast
            const float w1 = sAdj[1][j];
            acc0 = fmaf(w0, silu_f(pim0 + pjv), acc0);
            acc1 = fmaf(w1, silu_f(pim1 + pjv), acc1);
        }
    }

    sRed[0][t] = acc0;
    sRed[1][t] = acc1;
    __syncthreads();
    if (t < 128) {
        sS[t] = (sRed[0][t] + sRed[0][t + 128]) * inv0;
    } else {
        const int k = t - 128;
        sS[MM + k] = (sRed[1][k] + sRed[1][k + 128]) * inv1;
    }
    // sS visibility covered by first staging sync below.

    // ---- Phase B: 3-stage head. k = m, row = half. Full dot per thread.
    const float betr = (half == 0) ? bet0 : bet1;

    // Stage 1: magg = S@W2 + beta*b2  (sS -> sB)
    float acc = betr * b2k;
    for (int c = 0; c < 2; ++c) {
        __syncthreads();
        const float4* g = (const float4*)(W2 + (size_t)c * 64 * MM);
        float4* l = (float4*)sStage;
        #pragma unroll
        for (int i = 0; i < 8; ++i) l[t + 256 * i] = g[t + 256 * i];
        __syncthreads();
        #pragma unroll 8
        for (int dd = 0; dd < 64; ++dd) {
            const int d = c * 64 + dd;
            acc = fmaf(sS[half * MM + d], sStage[dd * MM + m], acc);
        }
    }
    sB[half * MM + m] = acc;

    // Stage 2: t1 = silu(magg@Wc1 + bc1)  (sB -> sS)
    acc = bc1k;
    for (int c = 0; c < 2; ++c) {
        __syncthreads();               // covers sB writes on c=0
        const float4* g = (const float4*)(Wc1 + (size_t)c * 64 * MM);
        float4* l = (float4*)sStage;
        #pragma unroll
        for (int i = 0; i < 8; ++i) l[t + 256 * i] = g[t + 256 * i];
        __syncthreads();
        #pragma unroll 8
        for (int dd = 0; dd < 64; ++dd) {
            const int d = c * 64 + dd;
            acc = fmaf(sB[half * MM + d], sStage[dd * MM + m], acc);
        }
    }
    __syncthreads();                   // sS readers (stage 1 src) done
    sS[half * MM + m] = silu_f(acc);

    // Stage 3: out = t1@Wc2 + bc2
    acc = bc2k;
    for (int c = 0; c < 2; ++c) {
        __syncthreads();               // covers sS writes on c=0
        const float4* g = (const float4*)(Wc2 + (size_t)c * 64 * MM);
        float4* l = (float4*)sStage;
        #pragma unroll
        for (int i = 0; i < 8; ++i) l[t + 256 * i] = g[t + 256 * i];
        __syncthreads();
        #pragma unroll 8
        for (int dd = 0; dd < 64; ++dd) {
            const int d = c * 64 + dd;
            acc = fmaf(sS[half * MM + d], sStage[dd * MM + m], acc);
        }
    }
    out[(size_t)(row0 + half) * CC + m] = acc;
}

extern "C" void kernel_launch(void* const* d_in, const int* in_sizes, int n_in,
                              void* d_out, int out_size, void* d_ws, size_t ws_size,
                              hipStream_t stream) {
    const float* h   = (const float*)d_in[0];
    const float* adj = (const float*)d_in[1];
    const float* W1a = (const float*)d_in[2];
    const float* W1b = (const float*)d_in[3];
    const float* b1  = (const float*)d_in[4];
    const float* W2  = (const float*)d_in[5];
    const float* b2  = (const float*)d_in[6];
    const float* Wc1 = (const float*)d_in[7];
    const float* bc1 = (const float*)d_in[8];
    const float* Wc2 = (const float*)d_in[9];
    const float* bc2 = (const float*)d_in[10];
    float* out = (float*)d_out;

    // Workspace (floats): pibias[1024*128] | pj[1024*128]
    float* ws = (float*)d_ws;
    float* pibias = ws;
    float* pj     = ws + (size_t)ROWS * MM;

    k_proj<<<ROWS / 2, 256, 0, stream>>>(h, W1a, W1b, b1, pibias, pj);
    k_msgout<<<ROWS / 2, 256, 0, stream>>>(adj, pibias, pj, W2, b2, Wc1, bc1,
                                           Wc2, bc2, out);
}